// Round 2
// baseline (241.504 us; speedup 1.0000x reference)
//
#include <hip/hip_runtime.h>
#include <hip/hip_bf16.h>

// LayerNorm(K=128) + Linear(128x128) fused, fp32 in/out, bf16 MFMA inside.
// Barrier-free main loop: x loaded directly in MFMA fragment layout
// (2-round shuffle LN), ln_weight folded into staged B, ln_bias folded into
// accumulator init. 512 MiB HBM traffic -> ~85us floor, memory-bound.

#define K_DIM 128
#define N_DIM 128
#define LDS_STRIDE 136   // 128+8 bf16 pad: 68-dword row stride -> 2-way bank alias (free)
#define T_PER_WAVE 8     // 16-row tiles per wave; 4 waves/block -> 512 rows/block

typedef __attribute__((ext_vector_type(8))) short bf16x8;
typedef __attribute__((ext_vector_type(4))) float f32x4;

__device__ __forceinline__ unsigned short f2bf(float f) {
    union { float f; unsigned int u; } v; v.f = f;
    unsigned int u = v.u;
    return (unsigned short)((u + 0x7fffu + ((u >> 16) & 1u)) >> 16);  // RNE
}

__global__ __launch_bounds__(256, 4) void lnlin_kernel(
    const float* __restrict__ x, const float* __restrict__ lnw,
    const float* __restrict__ lnb, const float* __restrict__ B,
    float* __restrict__ out)
{
    __shared__ __align__(16) unsigned short sW[N_DIM * LDS_STRIDE]; // [n][k] bf16, W'=w*B transposed
    __shared__ __align__(16) float sCpart[8][N_DIM];
    __shared__ __align__(16) float sC[N_DIM];                       // c[n] = sum_k b[k]*B[k][n]

    const int tid = threadIdx.x;

    // --- stage W' = diag(lnw)*B  ->  LDS [n][k] bf16; partial c = lnb^T * B ---
    {
        const int n0 = (tid & 31) * 4;
        const int kb = tid >> 5;            // 0..7
        float4 cacc = make_float4(0.f, 0.f, 0.f, 0.f);
        #pragma unroll
        for (int p = 0; p < 16; ++p) {
            const int k = kb + p * 8;
            const float4 b4 = *(const float4*)(B + k * N_DIM + n0);
            const float wk = lnw[k];
            const float bk = lnb[k];
            sW[(n0 + 0) * LDS_STRIDE + k] = f2bf(b4.x * wk);
            sW[(n0 + 1) * LDS_STRIDE + k] = f2bf(b4.y * wk);
            sW[(n0 + 2) * LDS_STRIDE + k] = f2bf(b4.z * wk);
            sW[(n0 + 3) * LDS_STRIDE + k] = f2bf(b4.w * wk);
            cacc.x += bk * b4.x; cacc.y += bk * b4.y;
            cacc.z += bk * b4.z; cacc.w += bk * b4.w;
        }
        *(float4*)&sCpart[kb][n0] = cacc;
    }
    __syncthreads();
    if (tid < N_DIM) {
        float c = 0.f;
        #pragma unroll
        for (int g = 0; g < 8; ++g) c += sCpart[g][tid];
        sC[tid] = c;
    }
    __syncthreads();
    // ---- no barriers below this line: waves fully independent ----

    const int wave = tid >> 6;
    const int lane = tid & 63;
    const int m    = lane & 15;   // row within 16-row tile (= MFMA frag row & D col)
    const int kg   = lane >> 4;   // k-group 0..3

    const size_t rowBase = ((size_t)blockIdx.x * 4 + wave) * (T_PER_WAVE * 16) + m;
    const float* xp = x + rowBase * K_DIM + kg * 8;
    float*       op = out + rowBase * N_DIM;

    // first tile's x, directly in A-fragment layout: lane = (row m, k = kt*32+kg*8+0..7)
    float4 v[8];
    #pragma unroll
    for (int kt = 0; kt < 4; ++kt) {
        v[2 * kt]     = *(const float4*)(xp + kt * 32);
        v[2 * kt + 1] = *(const float4*)(xp + kt * 32 + 4);
    }

    for (int t = 0; t < T_PER_WAVE; ++t) {
        // --- LN stats: local 32-elem sums + 2 shuffle rounds across kg lanes ---
        float sum = 0.f, sq = 0.f;
        #pragma unroll
        for (int i = 0; i < 8; ++i) {
            const float4 w4 = v[i];
            sum += (w4.x + w4.y) + (w4.z + w4.w);
            sq  += w4.x * w4.x + w4.y * w4.y + w4.z * w4.z + w4.w * w4.w;
        }
        sum += __shfl_xor(sum, 16); sq += __shfl_xor(sq, 16);
        sum += __shfl_xor(sum, 32); sq += __shfl_xor(sq, 32);
        const float mean = sum * 0.0078125f;                        // /128
        const float var  = fmaxf(sq * 0.0078125f - mean * mean, 0.f);
        const float rstd = rsqrtf(var + 1e-5f);
        const float nm   = -mean * rstd;

        // --- normalize -> bf16 A-fragments (weight/bias already folded away) ---
        bf16x8 af[4];
        #pragma unroll
        for (int kt = 0; kt < 4; ++kt) {
            const float4 a = v[2 * kt], b = v[2 * kt + 1];
            union { unsigned short u[8]; bf16x8 f; } pk;
            pk.u[0] = f2bf(a.x * rstd + nm); pk.u[1] = f2bf(a.y * rstd + nm);
            pk.u[2] = f2bf(a.z * rstd + nm); pk.u[3] = f2bf(a.w * rstd + nm);
            pk.u[4] = f2bf(b.x * rstd + nm); pk.u[5] = f2bf(b.y * rstd + nm);
            pk.u[6] = f2bf(b.z * rstd + nm); pk.u[7] = f2bf(b.w * rstd + nm);
            af[kt] = pk.f;
        }

        // --- prefetch next tile (v regs dead now); hides HBM under MFMA phase ---
        if (t + 1 < T_PER_WAVE) {
            const float* xn = xp + (size_t)(t + 1) * 16 * K_DIM;
            #pragma unroll
            for (int kt = 0; kt < 4; ++kt) {
                v[2 * kt]     = *(const float4*)(xn + kt * 32);
                v[2 * kt + 1] = *(const float4*)(xn + kt * 32 + 4);
            }
        }

        // --- acc init = c[n] (broadcast ds_read), then MFMA, operands swapped ---
        f32x4 acc[8];
        #pragma unroll
        for (int nt = 0; nt < 8; ++nt)
            acc[nt] = *(const f32x4*)&sC[nt * 16 + kg * 4];
        #pragma unroll
        for (int kt = 0; kt < 4; ++kt) {
            #pragma unroll
            for (int nt = 0; nt < 8; ++nt) {
                const bf16x8 bw = *(const bf16x8*)&sW[(nt * 16 + m) * LDS_STRIDE + kt * 32 + kg * 8];
                acc[nt] = __builtin_amdgcn_mfma_f32_16x16x32_bf16(bw, af[kt], acc[nt], 0, 0, 0);
            }
        }

        // --- store: lane owns its row m, 4 consecutive cols per nt -> float4 ---
        float* o = op + (size_t)t * 16 * N_DIM;
        #pragma unroll
        for (int nt = 0; nt < 8; ++nt)
            *(float4*)(o + nt * 16 + kg * 4) = *(float4*)&acc[nt];
    }
}

extern "C" void kernel_launch(void* const* d_in, const int* in_sizes, int n_in,
                              void* d_out, int out_size, void* d_ws, size_t ws_size,
                              hipStream_t stream) {
    const float* x   = (const float*)d_in[0];
    const float* lnw = (const float*)d_in[1];
    const float* lnb = (const float*)d_in[2];
    const float* B   = (const float*)d_in[3];
    float* out = (float*)d_out;

    const int M = in_sizes[0] / K_DIM;                 // 524288
    const int grid = M / (T_PER_WAVE * 16 * 4);        // 1024 = exactly 4 blocks/CU

    hipLaunchKernelGGL(lnlin_kernel, dim3(grid), dim3(256), 0, stream,
                       x, lnw, lnb, B, out);
}

// Round 3
// 179.483 us; speedup vs baseline: 1.3456x; 1.3456x over previous
//
#include <hip/hip_runtime.h>

// LayerNorm(K=128) + Linear(128x128) fused, fp32 in/out, bf16 MFMA inside.
// Round 3: coalesced loads (round-1 style), barrier-free main loop
// (wave-private rows + wave-private sA), B pre-arranged in MFMA fragment
// order by a prep kernel (conflict-free ds_read_b128), float4 stores.
// Traffic floor 512 MiB -> ~85us at 6.3 TB/s.

#define K_DIM 128
#define N_DIM 128
#define SA_STRIDE 136   // shorts: 272B row stride, 16B-aligned, banks spread
#define T_PER_WAVE 8    // 16-row tiles per wave; 4 waves -> 512 rows/block

typedef __attribute__((ext_vector_type(8))) short bf16x8;
typedef __attribute__((ext_vector_type(4))) float f32x4;

static __device__ __forceinline__ unsigned short f2bf(float f) {
    union { float ff; unsigned int u; } v; v.ff = f;
    const unsigned int u = v.u;
    return (unsigned short)((u + 0x7fffu + ((u >> 16) & 1u)) >> 16);  // RNE
}

// prep: ws[0,32KB) = W' = diag(lnw)*B as bf16 in MFMA A-fragment order
//       slot g = (nt*4+kt)*64 + lane; shorts[r] = W'[nt*16+(lane&15)][kt*32+(lane>>4)*8+r]
//       ws[32KB,+512) = c[n] = sum_k lnb[k]*B[k][n]  (fp32)
__global__ void prep_kernel(const float* __restrict__ lnw, const float* __restrict__ lnb,
                            const float* __restrict__ B, unsigned short* __restrict__ wf,
                            float* __restrict__ c) {
    if (blockIdx.x < 8) {
        const int g  = blockIdx.x * 256 + threadIdx.x;   // 0..2047
        const int l  = g & 63;
        const int kt = (g >> 6) & 3;
        const int nt = g >> 8;
        const int n  = nt * 16 + (l & 15);
        const int k0 = kt * 32 + (l >> 4) * 8;
        union { unsigned short us[8]; int4 i4; } pk;
        #pragma unroll
        for (int r = 0; r < 8; ++r)
            pk.us[r] = f2bf(B[(k0 + r) * N_DIM + n] * lnw[k0 + r]);
        *(int4*)(wf + (size_t)g * 8) = pk.i4;
    } else if (threadIdx.x < N_DIM) {
        const int n = threadIdx.x;
        float acc = 0.f;
        #pragma unroll 8
        for (int k = 0; k < K_DIM; ++k)
            acc += lnb[k] * B[k * N_DIM + n];
        c[n] = acc;
    }
}

__global__ __launch_bounds__(256, 3) void lnlin_kernel(
    const float* __restrict__ x, const unsigned short* __restrict__ wf,
    const float* __restrict__ cg, float* __restrict__ out)
{
    __shared__ __align__(16) unsigned short sWf[2048 * 8];          // 32KB frag-order W'
    __shared__ __align__(16) unsigned short sA[4][16 * SA_STRIDE];  // wave-private x_hat

    const int tid  = threadIdx.x;
    const int wave = tid >> 6;
    const int lane = tid & 63;
    const int h    = lane >> 5;   // half-wave: row parity for loads
    const int s    = lane & 31;   // 16B chunk within row for loads
    const int m    = lane & 15;   // MFMA: row index (D col)
    const int kg   = lane >> 4;   // MFMA: k-group / D row-group

    const size_t waveRow0 = ((size_t)blockIdx.x * 4 + wave) * (T_PER_WAVE * 16);

    // issue first tile's x loads before staging (independent of LDS)
    const float* xp = x + waveRow0 * K_DIM + s * 4;
    float4 v[8];
    #pragma unroll
    for (int i = 0; i < 8; ++i)
        v[i] = *(const float4*)(xp + (2 * i + h) * K_DIM);

    // stage frag-order W': 8 x (16B coalesced global -> contiguous ds_write_b128)
    #pragma unroll
    for (int q = 0; q < 8; ++q) {
        const int idx = q * 256 + tid;
        *(int4*)(sWf + idx * 8) = *(const int4*)(wf + idx * 8);
    }
    // c kept in registers: lane needs c[nt*16 + kg*4 .. +3] (matches D layout)
    f32x4 c[8];
    #pragma unroll
    for (int nt = 0; nt < 8; ++nt)
        c[nt] = *(const f32x4*)(cg + nt * 16 + kg * 4);
    __syncthreads();   // the ONLY barrier

    unsigned short* sAw = sA[wave];
    float* op = out + waveRow0 * N_DIM;

    for (int t = 0; t < T_PER_WAVE; ++t) {
        // --- LN: half-wave shuffle reduce per row (rows 2i+h), pack bf16 ---
        ushort4 pk[8];
        #pragma unroll
        for (int i = 0; i < 8; ++i) {
            const float4 w4 = v[i];
            float sum = (w4.x + w4.y) + (w4.z + w4.w);
            float sq  = w4.x * w4.x + w4.y * w4.y + w4.z * w4.z + w4.w * w4.w;
            #pragma unroll
            for (int mk = 1; mk < 32; mk <<= 1) {
                sum += __shfl_xor(sum, mk);
                sq  += __shfl_xor(sq,  mk);
            }
            const float mean = sum * 0.0078125f;                       // /128
            const float var  = fmaxf(sq * 0.0078125f - mean * mean, 0.f);
            const float rstd = rsqrtf(var + 1e-5f);
            const float nm   = -mean * rstd;
            pk[i].x = f2bf(w4.x * rstd + nm);
            pk[i].y = f2bf(w4.y * rstd + nm);
            pk[i].z = f2bf(w4.z * rstd + nm);
            pk[i].w = f2bf(w4.w * rstd + nm);
        }

        // --- prefetch next tile (v dead); HBM latency hides under MFMA ---
        if (t + 1 < T_PER_WAVE) {
            const float* xn = xp + (t + 1) * 16 * K_DIM;
            #pragma unroll
            for (int i = 0; i < 8; ++i)
                v[i] = *(const float4*)(xn + (2 * i + h) * K_DIM);
        }

        // --- x_hat -> wave-private LDS (no barrier: same-wave lgkmcnt order) ---
        #pragma unroll
        for (int i = 0; i < 8; ++i)
            *(ushort4*)(sAw + (2 * i + h) * SA_STRIDE + s * 4) = pk[i];

        // --- A-fragments: lane (m,kg) reads row m, k = kt*32+kg*8 ---
        bf16x8 af[4];
        #pragma unroll
        for (int kt = 0; kt < 4; ++kt)
            af[kt] = *(const bf16x8*)(sAw + m * SA_STRIDE + kt * 32 + kg * 8);

        // --- MFMA: A-operand = W' frags (contiguous lane*16+imm reads) ---
        f32x4 acc[8];
        #pragma unroll
        for (int nt = 0; nt < 8; ++nt)
            acc[nt] = c[nt];
        #pragma unroll
        for (int kt = 0; kt < 4; ++kt) {
            #pragma unroll
            for (int nt = 0; nt < 8; ++nt) {
                const bf16x8 bw = *(const bf16x8*)(sWf + ((nt * 4 + kt) * 64 + lane) * 8);
                acc[nt] = __builtin_amdgcn_mfma_f32_16x16x32_bf16(bw, af[kt], acc[nt], 0, 0, 0);
            }
        }

        // --- store: lane owns row m; 4 consecutive n per nt -> float4 ---
        float* o = op + (t * 16 + m) * N_DIM + kg * 4;
        #pragma unroll
        for (int nt = 0; nt < 8; ++nt)
            *(f32x4*)(o + nt * 16) = acc[nt];
    }
}

extern "C" void kernel_launch(void* const* d_in, const int* in_sizes, int n_in,
                              void* d_out, int out_size, void* d_ws, size_t ws_size,
                              hipStream_t stream) {
    const float* x   = (const float*)d_in[0];
    const float* lnw = (const float*)d_in[1];
    const float* lnb = (const float*)d_in[2];
    const float* B   = (const float*)d_in[3];
    float* out = (float*)d_out;

    unsigned short* wf = (unsigned short*)d_ws;
    float* cg = (float*)((char*)d_ws + 32768);

    hipLaunchKernelGGL(prep_kernel, dim3(9), dim3(256), 0, stream, lnw, lnb, B, wf, cg);

    const int M = in_sizes[0] / K_DIM;                  // 524288
    const int grid = M / (4 * T_PER_WAVE * 16);         // 1024
    hipLaunchKernelGGL(lnlin_kernel, dim3(grid), dim3(256), 0, stream, x, wf, cg, out);
}